// Round 1
// baseline (3406.724 us; speedup 1.0000x reference)
//
#include <hip/hip_runtime.h>

typedef __attribute__((ext_vector_type(4))) float f32x4;
typedef __attribute__((ext_vector_type(8))) short short8;

#define VOCAB 50257
#define HDIM 512
#define TLEN 1024
#define RNN_WGS 16

static __device__ __forceinline__ unsigned short f2bf(float f) {
  unsigned u = __float_as_uint(f);
  u += 0x7fffu + ((u >> 16) & 1u);           // round-to-nearest-even
  return (unsigned short)(u >> 16);
}
static __device__ __forceinline__ float b2f(short s) {
  return __uint_as_float(((unsigned)(unsigned short)s) << 16);
}

// ---------------------------------------------------------------- init
__global__ __launch_bounds__(256) void init_kernel(int* __restrict__ counters) {
  int i = blockIdx.x * 256 + threadIdx.x;
  if (i < TLEN) counters[i] = 0;
}

// ---------------------------------------------------------------- phase A: recurrence
// 16 WGs, each owns 32 output columns of W_hh (bf16 in LDS).
// Per step: matvec slice -> tanh -> publish 32 floats (agent-scope) -> counter
// handshake -> read full h[t] back.
__global__ __launch_bounds__(256) void rnn_kernel(
    const int* __restrict__ tokens, const float* __restrict__ h0,
    const float* __restrict__ emb_table, const float* __restrict__ Whh,
    const float* __restrict__ bh, float* __restrict__ Hout,
    int* __restrict__ counters)
{
  const int g = blockIdx.x;
  const int tid = threadIdx.x;
  const int col = tid & 31;          // 0..31 (column within slice)
  const int kk = tid >> 5;           // 0..7  (k-range owner: 64 k each)
  const int colg = g * 32 + col;
  const int wvw = kk >> 1;           // wave id 0..3
  const int kkl = kk & 1;

  __shared__ short8 Wl[2048];        // 32 KB: bf16 W slice, lane-ordered 16B chunks
  __shared__ float hl[HDIM];
  __shared__ float pl[256];

  // preload W slice as bf16 into lane-ordered chunk layout:
  // element (k, col) -> chunk ((k>>7)*8 + ((k>>3)&7))*64 + ((k>>6)&1)*32 + col, sub k&7
  unsigned short* Wls = (unsigned short*)Wl;
  for (int k = kk; k < HDIM; k += 8) {
    float w = Whh[k * HDIM + colg];
    int chunk = ((k >> 7) * 8 + ((k >> 3) & 7)) * 64 + ((k >> 6) & 1) * 32 + col;
    Wls[chunk * 8 + (k & 7)] = f2bf(w);
  }
  hl[tid] = h0[tid];
  hl[tid + 256] = h0[tid + 256];
  __syncthreads();

  for (int t = 0; t < TLEN; ++t) {
    float e = 0.f;
    if (tid < 32) {
      int tok = tokens[t];
      e = emb_table[(size_t)tok * HDIM + colg] + bh[colg];
    }
    // matvec: thread (col,kk) accumulates k in [kk*64, kk*64+64)
    float acc = 0.f;
#pragma unroll
    for (int i = 0; i < 8; ++i) {
      short8 w8 = Wl[(wvw * 8 + i) * 64 + kkl * 32 + col];
      f32x4 h1 = *(const f32x4*)&hl[kk * 64 + i * 8];
      f32x4 h2 = *(const f32x4*)&hl[kk * 64 + i * 8 + 4];
      acc += b2f(w8[0]) * h1.x + b2f(w8[1]) * h1.y + b2f(w8[2]) * h1.z + b2f(w8[3]) * h1.w
           + b2f(w8[4]) * h2.x + b2f(w8[5]) * h2.y + b2f(w8[6]) * h2.z + b2f(w8[7]) * h2.w;
    }
    pl[tid] = acc;
    __syncthreads();
    if (tid < 32) {
      float z = e;
#pragma unroll
      for (int q = 0; q < 8; ++q) z += pl[q * 32 + col];
      float h = tanhf(z);
      __hip_atomic_store(&Hout[t * HDIM + colg], h, __ATOMIC_RELAXED,
                         __HIP_MEMORY_SCOPE_AGENT);
    }
    __syncthreads();   // all 32 agent-scope stores complete before flag
    if (tid == 0) {
      __hip_atomic_fetch_add(&counters[t], 1, __ATOMIC_RELEASE,
                             __HIP_MEMORY_SCOPE_AGENT);
      while (__hip_atomic_load(&counters[t], __ATOMIC_ACQUIRE,
                               __HIP_MEMORY_SCOPE_AGENT) < RNN_WGS) { }
    }
    __syncthreads();
    if (t < TLEN - 1) {
      hl[tid * 2] = __hip_atomic_load(&Hout[t * HDIM + tid * 2], __ATOMIC_RELAXED,
                                      __HIP_MEMORY_SCOPE_AGENT);
      hl[tid * 2 + 1] = __hip_atomic_load(&Hout[t * HDIM + tid * 2 + 1], __ATOMIC_RELAXED,
                                          __HIP_MEMORY_SCOPE_AGENT);
      __syncthreads();
    }
  }
}

// ---------------------------------------------------------------- phase B: attention + X pack
// One WG per timestep t. fp32 throughout; writes X=[h|ctx] as bf16.
__global__ __launch_bounds__(256) void attn_kernel(
    const float* __restrict__ Hall, unsigned short* __restrict__ Xbf)
{
  const int t = blockIdx.x;
  const int tid = threadIdx.x;
  const int lane = tid & 63;
  const int wave = tid >> 6;
  __shared__ float ht[HDIM];
  __shared__ float sc[TLEN];
  __shared__ float red[8];

  float h_a = Hall[(size_t)t * HDIM + tid];
  float h_b = Hall[(size_t)t * HDIM + tid + 256];
  ht[tid] = h_a; ht[tid + 256] = h_b;
  Xbf[(size_t)t * 1024 + tid] = f2bf(h_a);
  Xbf[(size_t)t * 1024 + tid + 256] = f2bf(h_b);
  __syncthreads();

  if (t == 0) {                       // empty cache -> ctx = 0
    Xbf[512 + tid] = 0;
    Xbf[512 + tid + 256] = 0;
    return;
  }

  const f32x4* ht4 = (const f32x4*)ht;
  float lmax = -1e30f;
  for (int s = tid; s < t; s += 256) {
    const f32x4* hp = (const f32x4*)(Hall + (size_t)s * HDIM);
    float d = 0.f;
#pragma unroll 8
    for (int q = 0; q < HDIM / 4; ++q) {
      f32x4 a = hp[q]; f32x4 b = ht4[q];
      d += a.x * b.x + a.y * b.y + a.z * b.z + a.w * b.w;
    }
    sc[s] = d;
    lmax = fmaxf(lmax, d);
  }
  for (int off = 32; off > 0; off >>= 1) lmax = fmaxf(lmax, __shfl_down(lmax, off));
  if (lane == 0) red[wave] = lmax;
  __syncthreads();
  float m = fmaxf(fmaxf(red[0], red[1]), fmaxf(red[2], red[3]));
  __syncthreads();

  float lsum = 0.f;
  for (int s = tid; s < t; s += 256) {
    float ev = __expf(sc[s] - m);
    sc[s] = ev;
    lsum += ev;
  }
  for (int off = 32; off > 0; off >>= 1) lsum += __shfl_down(lsum, off);
  if (lane == 0) red[wave] = lsum;
  __syncthreads();
  float Z = red[0] + red[1] + red[2] + red[3];
  float inv = 1.0f / Z;

  float a0 = 0.f, a1 = 0.f;
#pragma unroll 4
  for (int s = 0; s < t; ++s) {
    float w = sc[s];
    a0 += w * Hall[(size_t)s * HDIM + tid];
    a1 += w * Hall[(size_t)s * HDIM + tid + 256];
  }
  Xbf[(size_t)t * 1024 + 512 + tid] = f2bf(a0 * inv);
  Xbf[(size_t)t * 1024 + 512 + tid + 256] = f2bf(a1 * inv);
}

// ---------------------------------------------------------------- W_c cast+transpose
// [2H, VOCAB] fp32 -> [VOCAB, 2H] bf16 so GEMM B-frags read k-contiguous.
__global__ __launch_bounds__(256) void convT_kernel(
    const float* __restrict__ Wc, unsigned short* __restrict__ WT)
{
  const int n0 = blockIdx.x * 64;
  const int k0 = blockIdx.y * 64;
  const int tid = threadIdx.x;
  __shared__ float tile[64][65];
  const int c = tid & 63;
  const int r = tid >> 6;            // 0..3
#pragma unroll
  for (int it = 0; it < 16; ++it) {
    int row = it * 4 + r;
    int n = n0 + c;
    tile[row][c] = (n < VOCAB) ? Wc[(size_t)(k0 + row) * VOCAB + n] : 0.f;
  }
  __syncthreads();
#pragma unroll
  for (int it = 0; it < 16; ++it) {
    int nr = it * 4 + r;
    int n = n0 + nr;
    if (n < VOCAB) WT[(size_t)n * 1024 + k0 + c] = f2bf(tile[c][nr]);
  }
}

// ---------------------------------------------------------------- phase C: MFMA GEMM
// out[T,VOCAB] = X[T,2H] @ Wc[2H,VOCAB] + bias.  BM=BN=128, BK=64,
// 4 waves 2x2, 64x64/wave as 4x4 frags of mfma_f32_16x16x32_bf16.
__global__ __launch_bounds__(256) void gemm_kernel(
    const unsigned short* __restrict__ Xbf, const unsigned short* __restrict__ WT,
    const float* __restrict__ bias, float* __restrict__ out)
{
  const int n0 = blockIdx.x * 128;
  const int m0 = blockIdx.y * 128;
  const int tid = threadIdx.x;
  const int lane = tid & 63;
  const int wave = tid >> 6;
  const int wm = wave >> 1, wn = wave & 1;
  const int r15 = lane & 15, kq = lane >> 4;

  __shared__ short As[128 * 72];     // stride 72 shorts = 144B (16B aligned)
  __shared__ short Bs[128 * 72];

  f32x4 acc[4][4] = {};

  for (int kb = 0; kb < 16; ++kb) {
#pragma unroll
    for (int j = 0; j < 4; ++j) {
      int slot = tid + 256 * j;
      int row = slot >> 3, c8 = slot & 7;
      short8 va = *(const short8*)(Xbf + (size_t)(m0 + row) * 1024 + kb * 64 + c8 * 8);
      *(short8*)&As[row * 72 + c8 * 8] = va;
      int n = n0 + row;
      short8 vb = {};
      if (n < VOCAB)
        vb = *(const short8*)(WT + (size_t)n * 1024 + kb * 64 + c8 * 8);
      *(short8*)&Bs[row * 72 + c8 * 8] = vb;
    }
    __syncthreads();
#pragma unroll
    for (int s = 0; s < 2; ++s) {
      short8 af[4], bfr[4];
#pragma unroll
      for (int i = 0; i < 4; ++i)
        af[i] = *(const short8*)&As[(wm * 64 + i * 16 + r15) * 72 + s * 32 + kq * 8];
#pragma unroll
      for (int i = 0; i < 4; ++i)
        bfr[i] = *(const short8*)&Bs[(wn * 64 + i * 16 + r15) * 72 + s * 32 + kq * 8];
#pragma unroll
      for (int i = 0; i < 4; ++i)
#pragma unroll
        for (int jn = 0; jn < 4; ++jn)
          acc[i][jn] = __builtin_amdgcn_mfma_f32_16x16x32_bf16(af[i], bfr[jn], acc[i][jn], 0, 0, 0);
    }
    __syncthreads();
  }
  // epilogue: C/D layout col = lane&15, row = (lane>>4)*4 + reg
#pragma unroll
  for (int i = 0; i < 4; ++i) {
    int row = m0 + wm * 64 + i * 16 + kq * 4;
#pragma unroll
    for (int jn = 0; jn < 4; ++jn) {
      int col = n0 + wn * 64 + jn * 16 + r15;
      if (col < VOCAB) {
        float bv = bias[col];
#pragma unroll
        for (int rr = 0; rr < 4; ++rr)
          out[(size_t)(row + rr) * VOCAB + col] = acc[i][jn][rr] + bv;
      }
    }
  }
}

// ---------------------------------------------------------------- launch
extern "C" void kernel_launch(void* const* d_in, const int* in_sizes, int n_in,
                              void* d_out, int out_size, void* d_ws, size_t ws_size,
                              hipStream_t stream) {
  const int*   tokens   = (const int*)d_in[0];
  const float* h0       = (const float*)d_in[1];
  const float* emb      = (const float*)d_in[2];
  const float* Whh      = (const float*)d_in[3];
  const float* bh       = (const float*)d_in[4];
  const float* Wc       = (const float*)d_in[5];
  const float* bo       = (const float*)d_in[6];
  float* out = (float*)d_out;

  char* ws = (char*)d_ws;
  // ws layout (bytes): WT bf16 [50257*1024]   @ 0          (102,926,336)
  //                    H_all f32 [1024*512]   @ 102926336  (  2,097,152)
  //                    Xbf bf16 [1024*1024]   @ 105023488  (  2,097,152)
  //                    counters int [1024]    @ 107120640  (      4,096)
  unsigned short* WT   = (unsigned short*)(ws);
  float*          Hall = (float*)(ws + 102926336);
  unsigned short* Xbf  = (unsigned short*)(ws + 105023488);
  int*            cnt  = (int*)(ws + 107120640);

  init_kernel<<<dim3(4), dim3(256), 0, stream>>>(cnt);
  rnn_kernel<<<dim3(RNN_WGS), dim3(256), 0, stream>>>(tokens, h0, emb, Whh, bh, Hall, cnt);
  attn_kernel<<<dim3(TLEN), dim3(256), 0, stream>>>(Hall, Xbf);
  convT_kernel<<<dim3(786, 16), dim3(256), 0, stream>>>(Wc, WT);
  gemm_kernel<<<dim3(393, 8), dim3(256), 0, stream>>>(Xbf, WT, bo, out);
}

// Round 2
// 2518.431 us; speedup vs baseline: 1.3527x; 1.3527x over previous
//
#include <hip/hip_runtime.h>

typedef __attribute__((ext_vector_type(4))) float f32x4;
typedef __attribute__((ext_vector_type(8))) short short8;
typedef unsigned long long u64;

#define VOCAB 50257
#define HDIM 512
#define TLEN 1024
#define RNN_WGS 16
#define NANBITS 0x7fc00000u

#define GLOBAL_AS __attribute__((address_space(1)))
#define LDS_AS __attribute__((address_space(3)))
#define ASYNC16(gsrc, ldst) \
  __builtin_amdgcn_global_load_lds((const GLOBAL_AS void*)(gsrc), (LDS_AS void*)(ldst), 16, 0, 0)

static __device__ __forceinline__ unsigned short f2bf(float f) {
  unsigned u = __float_as_uint(f);
  u += 0x7fffu + ((u >> 16) & 1u);           // round-to-nearest-even
  return (unsigned short)(u >> 16);
}
static __device__ __forceinline__ float b2f(short s) {
  return __uint_as_float(((unsigned)(unsigned short)s) << 16);
}

// ---------------------------------------------------------------- init: Hall <- NaN sentinel
__global__ __launch_bounds__(256) void init_kernel(float* __restrict__ Hall) {
  int i = blockIdx.x * 256 + threadIdx.x;          // 512 blocks -> 1 float4 each
  f32x4 v = {__uint_as_float(NANBITS), __uint_as_float(NANBITS),
             __uint_as_float(NANBITS), __uint_as_float(NANBITS)};
  ((f32x4*)Hall)[i] = v;
}

// ---------------------------------------------------------------- phase A: recurrence
// 16 WGs x 32 cols. Data-is-the-flag sync: producers store h (agent scope),
// consumers poll row t until no lane holds the NaN sentinel.
__global__ __launch_bounds__(256) void rnn_kernel(
    const int* __restrict__ tokens, const float* __restrict__ h0,
    const float* __restrict__ emb_table, const float* __restrict__ Whh,
    const float* __restrict__ bh, float* __restrict__ Hout)
{
  const int g = blockIdx.x;
  const int tid = threadIdx.x;
  const int col = tid & 31;          // 0..31 (column within slice)
  const int kk = tid >> 5;           // 0..7  (k-range owner: 64 k each)
  const int colg = g * 32 + col;
  const int wvw = kk >> 1;
  const int kkl = kk & 1;

  __shared__ short8 Wl[2048];        // 32 KB bf16 W slice, lane-ordered 16B chunks
  __shared__ float hl[HDIM];
  __shared__ float pl[256];

  unsigned short* Wls = (unsigned short*)Wl;
  for (int k = kk; k < HDIM; k += 8) {
    float w = Whh[k * HDIM + colg];
    int chunk = ((k >> 7) * 8 + ((k >> 3) & 7)) * 64 + ((k >> 6) & 1) * 32 + col;
    Wls[chunk * 8 + (k & 7)] = f2bf(w);
  }
  hl[tid] = h0[tid];
  hl[tid + 256] = h0[tid + 256];

  float e = 0.f;
  if (tid < 32) e = emb_table[(size_t)tokens[0] * HDIM + colg] + bh[colg];
  __syncthreads();

  for (int t = 0; t < TLEN; ++t) {
    // matvec: thread (col,kk) accumulates k in [kk*64, kk*64+64)
    float acc = 0.f;
#pragma unroll
    for (int i = 0; i < 8; ++i) {
      short8 w8 = Wl[(wvw * 8 + i) * 64 + kkl * 32 + col];
      f32x4 h1 = *(const f32x4*)&hl[kk * 64 + i * 8];
      f32x4 h2 = *(const f32x4*)&hl[kk * 64 + i * 8 + 4];
      acc += b2f(w8[0]) * h1.x + b2f(w8[1]) * h1.y + b2f(w8[2]) * h1.z + b2f(w8[3]) * h1.w
           + b2f(w8[4]) * h2.x + b2f(w8[5]) * h2.y + b2f(w8[6]) * h2.z + b2f(w8[7]) * h2.w;
    }
    pl[tid] = acc;
    __syncthreads();
    if (tid < 32) {
      float z = e;
#pragma unroll
      for (int q = 0; q < 8; ++q) z += pl[q * 32 + col];
      float h = tanhf(z);
      __hip_atomic_store(&Hout[t * HDIM + colg], h, __ATOMIC_RELAXED,
                         __HIP_MEMORY_SCOPE_AGENT);
      if (t + 1 < TLEN)              // prefetch next embedding under the poll
        e = emb_table[(size_t)tokens[t + 1] * HDIM + colg] + bh[colg];
    }
    if (t < TLEN - 1) {
      const u64* p = (const u64*)(Hout + t * HDIM) + tid;
      u64 v;
      do {
        v = __hip_atomic_load(p, __ATOMIC_RELAXED, __HIP_MEMORY_SCOPE_AGENT);
      } while (((unsigned)v == NANBITS) || ((unsigned)(v >> 32) == NANBITS));
      *(u64*)&hl[2 * tid] = v;
    }
    __syncthreads();
  }
}

// ---------------------------------------------------------------- phase B: attention + X pack
__global__ __launch_bounds__(256) void attn_kernel(
    const float* __restrict__ Hall, unsigned short* __restrict__ Xbf)
{
  const int t = blockIdx.x;
  const int tid = threadIdx.x;
  const int lane = tid & 63;
  const int wave = tid >> 6;
  __shared__ float ht[HDIM];
  __shared__ float sc[TLEN];
  __shared__ float red[8];

  float h_a = Hall[(size_t)t * HDIM + tid];
  float h_b = Hall[(size_t)t * HDIM + tid + 256];
  ht[tid] = h_a; ht[tid + 256] = h_b;
  Xbf[(size_t)t * 1024 + tid] = f2bf(h_a);
  Xbf[(size_t)t * 1024 + tid + 256] = f2bf(h_b);
  __syncthreads();

  if (t == 0) {
    Xbf[512 + tid] = 0;
    Xbf[512 + tid + 256] = 0;
    return;
  }

  const f32x4* ht4 = (const f32x4*)ht;
  float lmax = -1e30f;
  for (int s = tid; s < t; s += 256) {
    const f32x4* hp = (const f32x4*)(Hall + (size_t)s * HDIM);
    float d = 0.f;
#pragma unroll 8
    for (int q = 0; q < HDIM / 4; ++q) {
      f32x4 a = hp[q]; f32x4 b = ht4[q];
      d += a.x * b.x + a.y * b.y + a.z * b.z + a.w * b.w;
    }
    sc[s] = d;
    lmax = fmaxf(lmax, d);
  }
  for (int off = 32; off > 0; off >>= 1) lmax = fmaxf(lmax, __shfl_down(lmax, off));
  if (lane == 0) red[wave] = lmax;
  __syncthreads();
  float m = fmaxf(fmaxf(red[0], red[1]), fmaxf(red[2], red[3]));
  __syncthreads();

  float lsum = 0.f;
  for (int s = tid; s < t; s += 256) {
    float ev = __expf(sc[s] - m);
    sc[s] = ev;
    lsum += ev;
  }
  for (int off = 32; off > 0; off >>= 1) lsum += __shfl_down(lsum, off);
  if (lane == 0) red[wave] = lsum;
  __syncthreads();
  float Z = red[0] + red[1] + red[2] + red[3];
  float inv = 1.0f / Z;

  float a0 = 0.f, a1 = 0.f;
#pragma unroll 4
  for (int s = 0; s < t; ++s) {
    float w = sc[s];
    a0 += w * Hall[(size_t)s * HDIM + tid];
    a1 += w * Hall[(size_t)s * HDIM + tid + 256];
  }
  Xbf[(size_t)t * 1024 + 512 + tid] = f2bf(a0 * inv);
  Xbf[(size_t)t * 1024 + 512 + tid + 256] = f2bf(a1 * inv);
}

// ---------------------------------------------------------------- W_c cast+transpose
__global__ __launch_bounds__(256) void convT_kernel(
    const float* __restrict__ Wc, unsigned short* __restrict__ WT)
{
  const int n0 = blockIdx.x * 64;
  const int k0 = blockIdx.y * 64;
  const int tid = threadIdx.x;
  __shared__ float tile[64][65];
  const int c = tid & 63;
  const int r = tid >> 6;
#pragma unroll
  for (int it = 0; it < 16; ++it) {
    int row = it * 4 + r;
    int n = n0 + c;
    tile[row][c] = (n < VOCAB) ? Wc[(size_t)(k0 + row) * VOCAB + n] : 0.f;
  }
  __syncthreads();
#pragma unroll
  for (int it = 0; it < 16; ++it) {
    int nr = it * 4 + r;
    int n = n0 + nr;
    if (n < VOCAB) WT[(size_t)n * 1024 + k0 + c] = f2bf(tile[c][nr]);
  }
}

// ---------------------------------------------------------------- phase C: MFMA GEMM (m97-style)
// out[T,VOCAB] = X[T,2H] @ Wc + bias. BM=BN=128, BK=64, async global->LDS,
// LDS layout [kchunk][row] (lane-contiguous 16B slots, conflict-free b128 reads).
__global__ __launch_bounds__(256) void gemm_kernel(
    const unsigned short* __restrict__ Xbf, const unsigned short* __restrict__ WT,
    const float* __restrict__ bias, float* __restrict__ out)
{
  const int n0 = blockIdx.x * 128;
  const int m0 = blockIdx.y * 128;
  const int tid = threadIdx.x;
  const int lane = tid & 63;
  const int wave = tid >> 6;
  const int wm = wave >> 1, wn = wave & 1;
  const int r15 = lane & 15, kq = lane >> 4;

  __shared__ short As[128 * 64];     // 16 KB, slot s = (kc<<7)|row, 8 shorts/slot
  __shared__ short Bs[128 * 64];

  f32x4 acc[4][4] = {};

  for (int kb = 0; kb < 16; ++kb) {
#pragma unroll
    for (int j = 0; j < 4; ++j) {
      int slot = tid + 256 * j;        // 0..1023
      int kc = slot >> 7, row = slot & 127;
      ASYNC16(Xbf + (size_t)(m0 + row) * 1024 + kb * 64 + kc * 8, As + slot * 8);
      int n = n0 + row; n = (n < VOCAB) ? n : (VOCAB - 1);   // clamp; garbage cols unstored
      ASYNC16(WT + (size_t)n * 1024 + kb * 64 + kc * 8, Bs + slot * 8);
    }
    __syncthreads();                   // drains vmcnt (global_load_lds) too
#pragma unroll
    for (int s = 0; s < 2; ++s) {
      short8 af[4], bfr[4];
#pragma unroll
      for (int i = 0; i < 4; ++i)
        af[i] = *(const short8*)&As[(((s * 4 + kq) << 7) + wm * 64 + i * 16 + r15) * 8];
#pragma unroll
      for (int i = 0; i < 4; ++i)
        bfr[i] = *(const short8*)&Bs[(((s * 4 + kq) << 7) + wn * 64 + i * 16 + r15) * 8];
#pragma unroll
      for (int i = 0; i < 4; ++i)
#pragma unroll
        for (int jn = 0; jn < 4; ++jn)
          acc[i][jn] = __builtin_amdgcn_mfma_f32_16x16x32_bf16(af[i], bfr[jn], acc[i][jn], 0, 0, 0);
    }
    __syncthreads();
  }
  // epilogue: C/D layout col = lane&15, row = (lane>>4)*4 + reg
#pragma unroll
  for (int i = 0; i < 4; ++i) {
    int row = m0 + wm * 64 + i * 16 + kq * 4;
#pragma unroll
    for (int jn = 0; jn < 4; ++jn) {
      int col = n0 + wn * 64 + jn * 16 + r15;
      if (col < VOCAB) {
        float bv = bias[col];
#pragma unroll
        for (int rr = 0; rr < 4; ++rr)
          out[(size_t)(row + rr) * VOCAB + col] = acc[i][jn][rr] + bv;
      }
    }
  }
}

// ---------------------------------------------------------------- launch
extern "C" void kernel_launch(void* const* d_in, const int* in_sizes, int n_in,
                              void* d_out, int out_size, void* d_ws, size_t ws_size,
                              hipStream_t stream) {
  const int*   tokens   = (const int*)d_in[0];
  const float* h0       = (const float*)d_in[1];
  const float* emb      = (const float*)d_in[2];
  const float* Whh      = (const float*)d_in[3];
  const float* bh       = (const float*)d_in[4];
  const float* Wc       = (const float*)d_in[5];
  const float* bo       = (const float*)d_in[6];
  float* out = (float*)d_out;

  char* ws = (char*)d_ws;
  // ws layout (bytes): WT bf16 [50257*1024]   @ 0          (102,926,336)
  //                    H_all f32 [1024*512]   @ 102926336  (  2,097,152)
  //                    Xbf bf16 [1024*1024]   @ 105023488  (  2,097,152)
  unsigned short* WT   = (unsigned short*)(ws);
  float*          Hall = (float*)(ws + 102926336);
  unsigned short* Xbf  = (unsigned short*)(ws + 105023488);

  init_kernel<<<dim3(512), dim3(256), 0, stream>>>(Hall);
  rnn_kernel<<<dim3(RNN_WGS), dim3(256), 0, stream>>>(tokens, h0, emb, Whh, bh, Hall);
  attn_kernel<<<dim3(TLEN), dim3(256), 0, stream>>>(Hall, Xbf);
  convT_kernel<<<dim3(786, 16), dim3(256), 0, stream>>>(Wc, WT);
  gemm_kernel<<<dim3(393, 8), dim3(256), 0, stream>>>(Xbf, WT, bo, out);
}